// Round 9
// baseline (4199.803 us; speedup 1.0000x reference)
//
#include <hip/hip_runtime.h>

#define NT 1024
#define NB 256            // 256 blocks x 1024 thr = 262144 = n; 1 block/CU
#define MAXIT 100
#define RTOL_F 1e-5f
#define BINS 256
// Degree-sorted SELL-64x1 (SELL-C-sigma, sigma=n): rows counting-sorted by
// degree; sorted slot tid is owned by thread tid; slice = 64 slots = one wave.
// Columns are REMAPPED into sorted space, so the CG loop is identical to the
// round-7 structure (2.04 ms): uncached 16B r gathers/stores through the MALL
// coherence point, 2 relaxed flag barriers/iter, no cache maintenance in-loop
// (round-8 lesson: per-iter wbL2/invL2 = +100%).

typedef float f4 __attribute__((ext_vector_type(4)));

__device__ __forceinline__ unsigned long long pk2(float a, float b) {
    return ((unsigned long long)__float_as_uint(b) << 32) | (unsigned long long)__float_as_uint(a);
}

// 16B uncached (coherence-point) load: ISSUE ONLY — result invalid until wait16.
__device__ __forceinline__ void ld16_cc(const f4* a, f4& d) {
    asm volatile("global_load_dwordx4 %0, %1, off sc0 sc1" : "=v"(d) : "v"(a));
}
// Wait for all VMEM; ties the 8 gather results so uses can't be hoisted above.
__device__ __forceinline__ void wait16x8(f4& a, f4& b, f4& c, f4& d,
                                         f4& e, f4& f, f4& g, f4& h) {
    asm volatile("s_waitcnt vmcnt(0)"
                 : "+v"(a), "+v"(b), "+v"(c), "+v"(d),
                   "+v"(e), "+v"(f), "+v"(g), "+v"(h));
}
// 16B uncached (coherence-point) store.
__device__ __forceinline__ void st16_cc(f4* a, f4 v) {
    asm volatile("global_store_dwordx4 %0, %1, off sc0 sc1" :: "v"(a), "v"(v) : "memory");
}

// ---- distributed flag barrier (relaxed spin; vmcnt drained by __syncthreads) ----
__device__ __forceinline__ void fbar(int* flags, int seq) {
    __syncthreads();
    if (threadIdx.x == 0)
        __hip_atomic_store(&flags[blockIdx.x], seq, __ATOMIC_RELAXED, __HIP_MEMORY_SCOPE_AGENT);
    if (threadIdx.x < 64) {
        const int b4 = threadIdx.x << 2;
        for (;;) {
            const int f0 = __hip_atomic_load(&flags[b4 + 0], __ATOMIC_RELAXED, __HIP_MEMORY_SCOPE_AGENT);
            const int f1 = __hip_atomic_load(&flags[b4 + 1], __ATOMIC_RELAXED, __HIP_MEMORY_SCOPE_AGENT);
            const int f2 = __hip_atomic_load(&flags[b4 + 2], __ATOMIC_RELAXED, __HIP_MEMORY_SCOPE_AGENT);
            const int f3 = __hip_atomic_load(&flags[b4 + 3], __ATOMIC_RELAXED, __HIP_MEMORY_SCOPE_AGENT);
            const bool ok = (f0 >= seq) && (f1 >= seq) && (f2 >= seq) && (f3 >= seq);
            if (__all(ok)) break;
            __builtin_amdgcn_s_sleep(1);
        }
    }
    __syncthreads();
}

// heavy variant for setup phases: full agent cache maintenance around arrival
__device__ __forceinline__ void fbar_heavy(int* flags, int seq) {
    __builtin_amdgcn_fence(__ATOMIC_RELEASE, "agent");
    fbar(flags, seq);
    __builtin_amdgcn_fence(__ATOMIC_ACQUIRE, "agent");
}

// Block-wide sum of two floats, broadcast to all threads (deterministic order).
__device__ __forceinline__ float2 block_sum2_bcast(float a, float b, float* smf) {
#pragma unroll
    for (int o = 32; o > 0; o >>= 1) { a += __shfl_down(a, o); b += __shfl_down(b, o); }
    __syncthreads();
    const int w = threadIdx.x >> 6;
    if ((threadIdx.x & 63) == 0) { smf[w] = a; smf[16 + w] = b; }
    __syncthreads();
    float ra = 0.f, rb = 0.f;
#pragma unroll
    for (int i = 0; i < 16; ++i) { ra += smf[i]; rb += smf[16 + i]; }
    return make_float2(ra, rb);
}

// Sum the NB packed (rho,mu) per-block partials — identical in every block.
__device__ __forceinline__ float2 sum_parts2(const unsigned long long* part, float* smf) {
    float a = 0.f, b = 0.f;
    if (threadIdx.x < NB) {
        unsigned long long u = __hip_atomic_load(&part[threadIdx.x], __ATOMIC_RELAXED,
                                                 __HIP_MEMORY_SCOPE_AGENT);
        a = __uint_as_float((unsigned)(u & 0xffffffffu));
        b = __uint_as_float((unsigned)(u >> 32));
    }
    return block_sum2_bcast(a, b, smf);
}

// Inclusive scan of one int per thread across the block (NT), via LDS.
__device__ __forceinline__ int block_incl_scan(int v, int* smi) {
    const int t = threadIdx.x;
    smi[t] = v;
    __syncthreads();
    for (int off = 1; off < NT; off <<= 1) {
        int add = (t >= off) ? smi[t - off] : 0;
        __syncthreads();
        v += add;
        smi[t] = v;
        __syncthreads();
    }
    return v;
}

// One SELL row SpMV, unroll-8 (J multiple of 8): 8 sell loads + 8x16B uncached
// gathers in flight per step.
__device__ __forceinline__ f4 spmv_row(const long long* __restrict__ bp0, int J,
                                       const f4* __restrict__ rq) {
    f4 a4 = {0.f, 0.f, 0.f, 0.f};
    for (int j = 0; j < J; j += 8) {
        long long e[8];
#pragma unroll
        for (int u = 0; u < 8; ++u) e[u] = bp0[(j + u) * 64];
        f4 g0, g1, g2, g3, g4, g5, g6, g7;
        ld16_cc(rq + (int)(e[0] & 0xffffffffLL), g0);
        ld16_cc(rq + (int)(e[1] & 0xffffffffLL), g1);
        ld16_cc(rq + (int)(e[2] & 0xffffffffLL), g2);
        ld16_cc(rq + (int)(e[3] & 0xffffffffLL), g3);
        ld16_cc(rq + (int)(e[4] & 0xffffffffLL), g4);
        ld16_cc(rq + (int)(e[5] & 0xffffffffLL), g5);
        ld16_cc(rq + (int)(e[6] & 0xffffffffLL), g6);
        ld16_cc(rq + (int)(e[7] & 0xffffffffLL), g7);
        wait16x8(g0, g1, g2, g3, g4, g5, g6, g7);
        a4 += __int_as_float((int)(e[0] >> 32)) * g0;
        a4 += __int_as_float((int)(e[1] >> 32)) * g1;
        a4 += __int_as_float((int)(e[2] >> 32)) * g2;
        a4 += __int_as_float((int)(e[3] >> 32)) * g3;
        a4 += __int_as_float((int)(e[4] >> 32)) * g4;
        a4 += __int_as_float((int)(e[5] >> 32)) * g5;
        a4 += __int_as_float((int)(e[6] >> 32)) * g6;
        a4 += __int_as_float((int)(e[7] >> 32)) * g7;
    }
    return a4;
}

__global__ void __launch_bounds__(NT, 4)
cg_solver_kernel(const float* __restrict__ values,
                 const f4* __restrict__ bvec,
                 const int* __restrict__ rowi,
                 const int* __restrict__ coli,
                 f4* __restrict__ x,                   // = d_out (original order)
                 f4* __restrict__ rst,                 // r rows in SORTED space
                 int* __restrict__ counts,             // n: row degrees
                 int* __restrict__ ridx,               // n: per-row scatter cursors
                 int* __restrict__ pos,                // n: orig row -> sorted slot
                 int* __restrict__ rord,               // n: sorted slot -> orig row
                 int* __restrict__ dh,                 // BINS: degree histogram
                 int* __restrict__ dcur,               // BINS: degree cursors
                 int* __restrict__ jarr,
                 int* __restrict__ soff,
                 unsigned long long* __restrict__ part, // NB packed (rho,mu) partials
                 int* __restrict__ flags,               // NB barrier flags (memset 0)
                 long long* __restrict__ sell,
                 int n, int nnz, int nslice)
{
    const int t = threadIdx.x;
    const int tid = blockIdx.x * NT + t;
    const int nth = gridDim.x * NT;          // == n
    __shared__ int smi[NT];
    __shared__ float smf[32];
    int seq = 0;

    // ---- A: zero counters ----
    for (int i = tid; i < n; i += nth) { counts[i] = 0; ridx[i] = 0; }
    if (tid < BINS) { dh[tid] = 0; dcur[tid] = 0; }
    fbar_heavy(flags, ++seq);

    // ---- B: row-degree histogram ----
    for (int e = tid; e < nnz; e += nth) atomicAdd(&counts[rowi[e]], 1);
    fbar_heavy(flags, ++seq);

    // ---- C: degree-bin histogram ----
    {
        const int d = min(counts[tid], BINS - 1);
        atomicAdd(&dh[d], 1);
    }
    fbar_heavy(flags, ++seq);

    // ---- D: block 0 scans degree bins -> dcur (exclusive offsets) ----
    if (blockIdx.x == 0) {
        int v = (t < BINS) ? dh[t] : 0;
        int incl = block_incl_scan(v, smi);
        if (t < BINS) dcur[t] = incl - v;
    }
    fbar_heavy(flags, ++seq);

    // ---- E: counting-sort scatter: row tid -> sorted slot ----
    {
        const int d = min(counts[tid], BINS - 1);
        const int slot = atomicAdd(&dcur[d], 1);
        pos[tid] = slot;
        rord[slot] = tid;
    }
    fbar_heavy(flags, ++seq);

    // ---- F: per-slice padded slot count (uniform degrees -> minimal pad) ----
    for (int s = tid; s < nslice; s += nth) {
        const int rb = s << 6;
        int m = 0;
#pragma unroll 4
        for (int i = 0; i < 64; ++i) m = max(m, counts[rord[rb + i]]);
        jarr[s] = (m + 7) & ~7;
    }
    fbar_heavy(flags, ++seq);

    // ---- G: block 0 scans slice sizes -> soff ----
    if (blockIdx.x == 0) {
        const int spt = (nslice + NT - 1) / NT;
        const int base = t * spt;
        int local = 0;
        for (int i = 0; i < spt; ++i) {
            int s = base + i;
            if (s < nslice) local += 64 * jarr[s];
        }
        int incl = block_incl_scan(local, smi);
        int run = incl - local;
        for (int i = 0; i < spt; ++i) {
            int s = base + i;
            if (s < nslice) { soff[s] = run; run += 64 * jarr[s]; }
        }
        if (t == NT - 1) soff[nslice] = incl;
    }
    fbar_heavy(flags, ++seq);

    // ---- H: zero-fill SELL ----
    {
        const int total = soff[nslice];
        for (int i = tid; i < total; i += nth) sell[i] = 0LL;
    }
    fbar_heavy(flags, ++seq);

    // ---- I: scatter COO -> SELL with columns remapped to sorted space ----
    for (int e = tid; e < nnz; e += nth) {
        const int rr = rowi[e];
        const int i = atomicAdd(&ridx[rr], 1);
        const int slot = pos[rr];
        const int p = soff[slot >> 6] + (i << 6) + (slot & 63);
        sell[p] = ((long long)__float_as_int(values[e]) << 32) | (unsigned int)pos[coli[e]];
    }
    fbar_heavy(flags, ++seq);

    // ---- CG-CG state: thread tid owns sorted slot tid (orig row rord[tid]) ----
    const int orig = rord[tid];
    const int wid = tid >> 6;
    const int lane = t & 63;
    const long long* __restrict__ bp0 = sell + soff[wid] + lane;
    const int J = jarr[wid];
    const f4* __restrict__ rq = rst;

    f4 rv = bvec[orig];                      // r_0 = b (register-resident)
    st16_cc(&rst[tid], rv);                  // publish in sorted space
    f4 pv = {0.f, 0.f, 0.f, 0.f};
    f4 sv = {0.f, 0.f, 0.f, 0.f};
    f4 xv = {0.f, 0.f, 0.f, 0.f};
    f4 wv;
    fbar_heavy(flags, ++seq);

    // ---- init-S: w0 = A r0; rho0 = r.r, mu0 = r.w ----
    {
        wv = spmv_row(bp0, J, rq);
        float rho_p = rv.x * rv.x + rv.y * rv.y + rv.z * rv.z + rv.w * rv.w;
        float mu_p  = rv.x * wv.x + rv.y * wv.y + rv.z * wv.z + rv.w * wv.w;
        float2 tot = block_sum2_bcast(rho_p, mu_p, smf);
        if (t == 0)
            __hip_atomic_store(&part[blockIdx.x], pk2(tot.x, tot.y), __ATOMIC_RELAXED, __HIP_MEMORY_SCOPE_AGENT);
    }
    fbar(flags, ++seq);

    float2 rm = sum_parts2(part, smf);       // (rho0, mu0) — identical in all blocks
    float rho = rm.x;
    const float tol2 = RTOL_F * RTOL_F * rho;
    float alpha = rho / rm.y;
    float beta = 0.f;

    int k = 0;
    while (rho > tol2 && k < MAXIT) {
        // --- U: register recurrences; publish new r (contiguous 16B uncached) ---
        pv = rv + beta * pv;
        sv = wv + beta * sv;
        xv = xv + alpha * pv;
        rv = rv - alpha * sv;
        st16_cc(&rst[tid], rv);
        fbar(flags, ++seq);   // all r published before any gather

        // --- S: w = A r + fused (r.r, r.w) partials ---
        wv = spmv_row(bp0, J, rq);
        {
            float rho_p = rv.x * rv.x + rv.y * rv.y + rv.z * rv.z + rv.w * rv.w;
            float mu_p  = rv.x * wv.x + rv.y * wv.y + rv.z * wv.z + rv.w * wv.w;
            float2 tot = block_sum2_bcast(rho_p, mu_p, smf);
            if (t == 0)
                __hip_atomic_store(&part[blockIdx.x], pk2(tot.x, tot.y), __ATOMIC_RELAXED, __HIP_MEMORY_SCOPE_AGENT);
        }
        fbar(flags, ++seq);   // partials published => all gathers of r_k done

        // --- scalars: identical in every block ---
        rm = sum_parts2(part, smf);          // (rho_{k+1}, mu_{k+1})
        beta = rm.x / rho;
        alpha = rm.x / (rm.y - beta * rm.x / alpha);
        rho = rm.x;
        ++k;
    }

    x[orig] = xv;   // single scattered write back to original order
}

extern "C" void kernel_launch(void* const* d_in, const int* in_sizes, int n_in,
                              void* d_out, int out_size, void* d_ws, size_t ws_size,
                              hipStream_t stream) {
    const float* values = (const float*)d_in[0];
    const f4* bvec      = (const f4*)d_in[1];
    const int* rowi     = (const int*)d_in[2];
    const int* coli     = (const int*)d_in[3];
    const int nnz = in_sizes[0];
    const int n   = in_sizes[1] / 4;  // F = 4
    const int nslice = n / 64;

    char* ws = (char*)d_ws;
    size_t off = 0;
    auto alloc = [&](size_t bytes) -> void* {
        off = (off + 255) & ~(size_t)255;
        void* pp = ws + off;
        off += bytes;
        return pp;
    };
    int* flags   = (int*)alloc((size_t)NB * 4);       // barrier flags (memset 0)
    f4* rst      = (f4*)alloc((size_t)n * 16);
    unsigned long long* part = (unsigned long long*)alloc((size_t)NB * 8);
    int* counts  = (int*)alloc((size_t)n * 4);
    int* ridx    = (int*)alloc((size_t)n * 4);
    int* pos     = (int*)alloc((size_t)n * 4);
    int* rord    = (int*)alloc((size_t)n * 4);
    int* dh      = (int*)alloc((size_t)BINS * 4);
    int* dcur    = (int*)alloc((size_t)BINS * 4);
    int* jarr    = (int*)alloc((size_t)nslice * 4);
    int* soff    = (int*)alloc((size_t)(nslice + 1) * 4);
    off = (off + 255) & ~(size_t)255;
    long long* sell = (long long*)(ws + off);         // rest of ws (~45 MB now)
    f4* x = (f4*)d_out;

    hipMemsetAsync(flags, 0, (size_t)NB * 4, stream);

    int n_ = n, nnz_ = nnz, nslice_ = nslice;
    void* args[] = {
        (void*)&values, (void*)&bvec, (void*)&rowi, (void*)&coli,
        (void*)&x, (void*)&rst,
        (void*)&counts, (void*)&ridx, (void*)&pos, (void*)&rord,
        (void*)&dh, (void*)&dcur, (void*)&jarr, (void*)&soff,
        (void*)&part, (void*)&flags,
        (void*)&sell, (void*)&n_, (void*)&nnz_, (void*)&nslice_
    };
    hipLaunchCooperativeKernel((void*)cg_solver_kernel, dim3(NB), dim3(NT),
                               args, 0, stream);
}

// Round 12
// 1856.077 us; speedup vs baseline: 2.2627x; 2.2627x over previous
//
#include <hip/hip_runtime.h>

#define NT 1024
#define NB 256            // 256 blocks x 1024 thr = 262144 = n; 1 block/CU
#define MAXIT 100
#define RTOL_F 1e-5f
// SELL-64x1, NATURAL row order (round-9 lesson: degree-sorting -> stragglers).
// entry j of row -> sell[soff[slice] + j*64 + (row & 63)]
//
// GHYSELS-VANROOSE pipelined CG — ONE flag barrier per iteration, legally:
//   w = A r and z = A s are maintained by register recurrences; the per-iter
//   SpMV is q_k = A w_k, and w_k was PUBLISHED AT THE END OF ITER k-1 (crossed
//   the previous barrier). So the single end-of-iter barrier sequences both
//   (w_{k+1} stores -> iter k+1 gathers) and (partials -> scalars).
//   Round-10/11 lesson: CG-CG's S-step needs the FRESH r, forcing 2 barriers;
//   GV is the formulation whose SpMV input is one-barrier-old by construction.
// w moves via 16B uncached (sc0 sc1) ops through the MALL coherence point; no
// cache maintenance in-loop (round-8 lesson: per-iter wbL2/invL2 = +100%).
// Per iter: read part[k&1] -> scalars; q = A w_k (gather wbuf[k&1]);
// register updates; store w_{k+1} -> wbuf[(k+1)&1]; publish part[(k+1)&1]; fbar.

typedef float f4 __attribute__((ext_vector_type(4)));

__device__ __forceinline__ unsigned long long pk2(float a, float b) {
    return ((unsigned long long)__float_as_uint(b) << 32) | (unsigned long long)__float_as_uint(a);
}

// 16B uncached (coherence-point) load: ISSUE ONLY — result invalid until wait16.
__device__ __forceinline__ void ld16_cc(const f4* a, f4& d) {
    asm volatile("global_load_dwordx4 %0, %1, off sc0 sc1" : "=v"(d) : "v"(a));
}
// Wait for all VMEM; ties the 8 gather results so uses can't be hoisted above.
__device__ __forceinline__ void wait16x8(f4& a, f4& b, f4& c, f4& d,
                                         f4& e, f4& f, f4& g, f4& h) {
    asm volatile("s_waitcnt vmcnt(0)"
                 : "+v"(a), "+v"(b), "+v"(c), "+v"(d),
                   "+v"(e), "+v"(f), "+v"(g), "+v"(h));
}
// 16B uncached (coherence-point) store.
__device__ __forceinline__ void st16_cc(f4* a, f4 v) {
    asm volatile("global_store_dwordx4 %0, %1, off sc0 sc1" :: "v"(a), "v"(v) : "memory");
}

// ---- distributed flag barrier (relaxed spin; vmcnt drained by __syncthreads) ----
__device__ __forceinline__ void fbar(int* flags, int seq) {
    __syncthreads();
    if (threadIdx.x == 0)
        __hip_atomic_store(&flags[blockIdx.x], seq, __ATOMIC_RELAXED, __HIP_MEMORY_SCOPE_AGENT);
    if (threadIdx.x < 64) {
        const int b4 = threadIdx.x << 2;
        for (;;) {
            const int f0 = __hip_atomic_load(&flags[b4 + 0], __ATOMIC_RELAXED, __HIP_MEMORY_SCOPE_AGENT);
            const int f1 = __hip_atomic_load(&flags[b4 + 1], __ATOMIC_RELAXED, __HIP_MEMORY_SCOPE_AGENT);
            const int f2 = __hip_atomic_load(&flags[b4 + 2], __ATOMIC_RELAXED, __HIP_MEMORY_SCOPE_AGENT);
            const int f3 = __hip_atomic_load(&flags[b4 + 3], __ATOMIC_RELAXED, __HIP_MEMORY_SCOPE_AGENT);
            const bool ok = (f0 >= seq) && (f1 >= seq) && (f2 >= seq) && (f3 >= seq);
            if (__all(ok)) break;
            __builtin_amdgcn_s_sleep(1);
        }
    }
    __syncthreads();
}

// heavy variant for setup phases: full agent cache maintenance around arrival
__device__ __forceinline__ void fbar_heavy(int* flags, int seq) {
    __builtin_amdgcn_fence(__ATOMIC_RELEASE, "agent");
    fbar(flags, seq);
    __builtin_amdgcn_fence(__ATOMIC_ACQUIRE, "agent");
}

// Block-wide sum of two floats, broadcast to all threads (deterministic order).
__device__ __forceinline__ float2 block_sum2_bcast(float a, float b, float* smf) {
#pragma unroll
    for (int o = 32; o > 0; o >>= 1) { a += __shfl_down(a, o); b += __shfl_down(b, o); }
    __syncthreads();
    const int w = threadIdx.x >> 6;
    if ((threadIdx.x & 63) == 0) { smf[w] = a; smf[16 + w] = b; }
    __syncthreads();
    float ra = 0.f, rb = 0.f;
#pragma unroll
    for (int i = 0; i < 16; ++i) { ra += smf[i]; rb += smf[16 + i]; }
    return make_float2(ra, rb);
}

// Sum NB packed (gamma,delta) partials from the given buffer — identical per block.
__device__ __forceinline__ float2 sum_parts2(const unsigned long long* buf, float* smf) {
    float a = 0.f, b = 0.f;
    if (threadIdx.x < NB) {
        unsigned long long u = __hip_atomic_load(&buf[threadIdx.x], __ATOMIC_RELAXED,
                                                 __HIP_MEMORY_SCOPE_AGENT);
        a = __uint_as_float((unsigned)(u & 0xffffffffu));
        b = __uint_as_float((unsigned)(u >> 32));
    }
    return block_sum2_bcast(a, b, smf);
}

// Inclusive scan of one int per thread across the block (NT), via LDS.
__device__ __forceinline__ int block_incl_scan(int v, int* smi) {
    const int t = threadIdx.x;
    smi[t] = v;
    __syncthreads();
    for (int off = 1; off < NT; off <<= 1) {
        int add = (t >= off) ? smi[t - off] : 0;
        __syncthreads();
        v += add;
        smi[t] = v;
        __syncthreads();
    }
    return v;
}

// One SELL row SpMV, unroll-8 (J multiple of 8) — round-7-proven pattern.
__device__ __forceinline__ f4 spmv_row(const long long* __restrict__ bp0, int J,
                                       const f4* __restrict__ rq) {
    f4 a4 = {0.f, 0.f, 0.f, 0.f};
    for (int j = 0; j < J; j += 8) {
        long long e[8];
#pragma unroll
        for (int u = 0; u < 8; ++u) e[u] = bp0[(j + u) * 64];
        f4 g0, g1, g2, g3, g4, g5, g6, g7;
        ld16_cc(rq + (int)(e[0] & 0xffffffffLL), g0);
        ld16_cc(rq + (int)(e[1] & 0xffffffffLL), g1);
        ld16_cc(rq + (int)(e[2] & 0xffffffffLL), g2);
        ld16_cc(rq + (int)(e[3] & 0xffffffffLL), g3);
        ld16_cc(rq + (int)(e[4] & 0xffffffffLL), g4);
        ld16_cc(rq + (int)(e[5] & 0xffffffffLL), g5);
        ld16_cc(rq + (int)(e[6] & 0xffffffffLL), g6);
        ld16_cc(rq + (int)(e[7] & 0xffffffffLL), g7);
        wait16x8(g0, g1, g2, g3, g4, g5, g6, g7);
        a4 += __int_as_float((int)(e[0] >> 32)) * g0;
        a4 += __int_as_float((int)(e[1] >> 32)) * g1;
        a4 += __int_as_float((int)(e[2] >> 32)) * g2;
        a4 += __int_as_float((int)(e[3] >> 32)) * g3;
        a4 += __int_as_float((int)(e[4] >> 32)) * g4;
        a4 += __int_as_float((int)(e[5] >> 32)) * g5;
        a4 += __int_as_float((int)(e[6] >> 32)) * g6;
        a4 += __int_as_float((int)(e[7] >> 32)) * g7;
    }
    return a4;
}

__global__ void __launch_bounds__(NT, 4)
cg_solver_kernel(const float* __restrict__ values,
                 const f4* __restrict__ bvec,
                 const int* __restrict__ rowi,
                 const int* __restrict__ coli,
                 f4* __restrict__ x,                   // = d_out
                 f4* __restrict__ wA,                  // w buffer (even-k gather source)
                 f4* __restrict__ wB,                  // w buffer (odd-k gather source)
                 int* __restrict__ counts,
                 int* __restrict__ ridx,
                 int* __restrict__ jarr,
                 int* __restrict__ soff,
                 unsigned long long* __restrict__ part, // 2*NB packed partials (dbuf)
                 int* __restrict__ flags,               // NB barrier flags (memset 0)
                 long long* __restrict__ sell,
                 int n, int nnz, int nslice)
{
    const int t = threadIdx.x;
    const int tid = blockIdx.x * NT + t;
    const int nth = gridDim.x * NT;          // == n
    __shared__ int smi[NT];
    __shared__ float smf[32];
    int seq = 0;

    // ---- Phase A: zero counters ----
    for (int i = tid; i < n; i += nth) { counts[i] = 0; ridx[i] = 0; }
    fbar_heavy(flags, ++seq);

    // ---- Phase B: histogram + keep b in registers; publish r0=b into wB
    //      (wB doubles as the init-SpMV source; first loop store overwrites it
    //       only after the post-init barrier) ----
    for (int e = tid; e < nnz; e += nth) atomicAdd(&counts[rowi[e]], 1);
    f4 rv = bvec[tid];                       // r_0 = b (register-resident)
    st16_cc(&wB[tid], rv);
    fbar_heavy(flags, ++seq);

    // ---- Phase C: per-slice padded slot count (multiple of 8 for unroll-8) ----
    for (int s = tid; s < nslice; s += nth) {
        const int rb = s << 6;
        int m = 0;
#pragma unroll 4
        for (int i = 0; i < 64; ++i) m = max(m, counts[rb + i]);
        jarr[s] = (m + 7) & ~7;
    }
    fbar_heavy(flags, ++seq);

    // ---- Phase D: block 0 scans slice sizes -> soff ----
    if (blockIdx.x == 0) {
        const int spt = (nslice + NT - 1) / NT;
        const int base = t * spt;
        int local = 0;
        for (int i = 0; i < spt; ++i) {
            int s = base + i;
            if (s < nslice) local += 64 * jarr[s];
        }
        int incl = block_incl_scan(local, smi);
        int run = incl - local;
        for (int i = 0; i < spt; ++i) {
            int s = base + i;
            if (s < nslice) { soff[s] = run; run += 64 * jarr[s]; }
        }
        if (t == NT - 1) soff[nslice] = incl;
    }
    fbar_heavy(flags, ++seq);

    // ---- Phase E: zero-fill SELL ----
    {
        const int total = soff[nslice];
        for (int i = tid; i < total; i += nth) sell[i] = 0LL;
    }
    fbar_heavy(flags, ++seq);

    // ---- Phase F: scatter COO -> SELL ----
    for (int e = tid; e < nnz; e += nth) {
        const int rr = rowi[e];
        const int i = atomicAdd(&ridx[rr], 1);
        const int pos = soff[rr >> 6] + (i << 6) + (rr & 63);
        sell[pos] = ((long long)__float_as_int(values[e]) << 32) | (unsigned int)coli[e];
    }
    fbar_heavy(flags, ++seq);

    // ---- GV state (all owner-local, registers; x written once at end) ----
    const int wid = tid >> 6;
    const int lane = t & 63;
    const long long* __restrict__ bp0 = sell + soff[wid] + lane;
    const int J = jarr[wid];

    f4 pv = {0.f, 0.f, 0.f, 0.f};
    f4 sv = {0.f, 0.f, 0.f, 0.f};
    f4 zv = {0.f, 0.f, 0.f, 0.f};
    f4 xv = {0.f, 0.f, 0.f, 0.f};
    f4 wv;

    // ---- init: w0 = A r0 (gather wB); store w0 -> wA (iter-0 source);
    //      publish part[0] = (gamma0 = r.r, delta0 = r.w) ----
    {
        wv = spmv_row(bp0, J, wB);
        st16_cc(&wA[tid], wv);
        float g_p = rv.x * rv.x + rv.y * rv.y + rv.z * rv.z + rv.w * rv.w;
        float d_p = rv.x * wv.x + rv.y * wv.y + rv.z * wv.z + rv.w * wv.w;
        float2 tot = block_sum2_bcast(g_p, d_p, smf);
        if (t == 0)
            __hip_atomic_store(&part[blockIdx.x], pk2(tot.x, tot.y), __ATOMIC_RELAXED, __HIP_MEMORY_SCOPE_AGENT);
    }
    fbar(flags, ++seq);

    float tol2 = 0.f;
    float rho_prev = 1.f;
    float alpha = 1.f;

    for (int k = 0;; ++k) {
        // --- scalars: read iter-k partials (closed since last fbar) ---
        float2 rm = sum_parts2(part + (k & 1) * NB, smf);  // (gamma_k, delta_k)
        if (k == 0) tol2 = RTOL_F * RTOL_F * rm.x;
        if (!(rm.x > tol2 && k < MAXIT)) break;
        const float beta = (k == 0) ? 0.f : rm.x / rho_prev;
        alpha = rm.x / (rm.y - beta * rm.x / alpha);       // beta=0 -> gamma/delta
        rho_prev = rm.x;

        // --- SpMV: q_k = A w_k, gathering wbuf[k&1] (published before last fbar) ---
        const f4* wq = (k & 1) ? wB : wA;
        f4 qv = spmv_row(bp0, J, wq);

        // --- GV register recurrences ---
        zv = qv + beta * zv;       // z = A s
        sv = wv + beta * sv;       // s = A p
        pv = rv + beta * pv;
        xv = xv + alpha * pv;
        rv = rv - alpha * sv;
        wv = wv - alpha * zv;      // w = A r maintained by recurrence

        // --- publish w_{k+1} (other buffer) + iter-(k+1) partials; ONE barrier ---
        f4* wt = (k & 1) ? wA : wB;
        st16_cc(&wt[tid], wv);
        {
            float g_p = rv.x * rv.x + rv.y * rv.y + rv.z * rv.z + rv.w * rv.w;
            float d_p = rv.x * wv.x + rv.y * wv.y + rv.z * wv.z + rv.w * wv.w;
            float2 tot = block_sum2_bcast(g_p, d_p, smf);
            if (t == 0)
                __hip_atomic_store(&part[((k + 1) & 1) * NB + blockIdx.x], pk2(tot.x, tot.y),
                                   __ATOMIC_RELAXED, __HIP_MEMORY_SCOPE_AGENT);
        }
        fbar(flags, ++seq);
    }

    x[tid] = xv;   // single write of the solution
}

extern "C" void kernel_launch(void* const* d_in, const int* in_sizes, int n_in,
                              void* d_out, int out_size, void* d_ws, size_t ws_size,
                              hipStream_t stream) {
    const float* values = (const float*)d_in[0];
    const f4* bvec      = (const f4*)d_in[1];
    const int* rowi     = (const int*)d_in[2];
    const int* coli     = (const int*)d_in[3];
    const int nnz = in_sizes[0];
    const int n   = in_sizes[1] / 4;  // F = 4
    const int nslice = n / 64;

    char* ws = (char*)d_ws;
    size_t off = 0;
    auto alloc = [&](size_t bytes) -> void* {
        off = (off + 255) & ~(size_t)255;
        void* pp = ws + off;
        off += bytes;
        return pp;
    };
    int* flags   = (int*)alloc((size_t)NB * 4);       // barrier flags (memset 0)
    f4* wA       = (f4*)alloc((size_t)n * 16);
    f4* wB       = (f4*)alloc((size_t)n * 16);
    unsigned long long* part = (unsigned long long*)alloc((size_t)2 * NB * 8);
    int* counts  = (int*)alloc((size_t)n * 4);
    int* ridx    = (int*)alloc((size_t)n * 4);
    int* jarr    = (int*)alloc((size_t)nslice * 4);
    int* soff    = (int*)alloc((size_t)(nslice + 1) * 4);
    off = (off + 255) & ~(size_t)255;
    long long* sell = (long long*)(ws + off);         // rest of ws (~65 MB)
    f4* x = (f4*)d_out;

    hipMemsetAsync(flags, 0, (size_t)NB * 4, stream);

    int n_ = n, nnz_ = nnz, nslice_ = nslice;
    void* args[] = {
        (void*)&values, (void*)&bvec, (void*)&rowi, (void*)&coli,
        (void*)&x, (void*)&wA, (void*)&wB,
        (void*)&counts, (void*)&ridx, (void*)&jarr, (void*)&soff,
        (void*)&part, (void*)&flags,
        (void*)&sell, (void*)&n_, (void*)&nnz_, (void*)&nslice_
    };
    hipLaunchCooperativeKernel((void*)cg_solver_kernel, dim3(NB), dim3(NT),
                               args, 0, stream);
}